// Round 15
// baseline (60.285 us; speedup 1.0000x reference)
//
#include <hip/hip_runtime.h>
#include <hip/hip_bf16.h>
#include <stdint.h>

// RefBasedDeepMetric: out[b] = ||x_b@W + b||^2 + mean_r||vref_r||^2 - 2*(x_b@W + b).t
// t = (mean_r refs_r)@W + b.  Two row-norm-reduced 4096x1024x1024 GEMMs, fused epilogues.
// R7: XCD co-location. R9: f32 A staged direct (cvt_pk). R10/R11: t via gated
// broadcast-MFMA; counted vmcnt(6). 44.6us. R8/R12/R13: in-kernel cross-block sync
// ALL regressed — dependencies stay at launch boundaries.
// R14: k_colsum eliminated (k_main reduces 32 partials itself, +1.5us validated) BUT
//      prep refs branch at 32 blocks was 8x under-parallelized (+13us). 50.8us.
// R15: prep refs branch re-parallelized: 256 blocks = 32 row-chunks x 8 col-slices,
//      64KB each, non-overlapping deterministic stores into the same 32x1024 cspart.
//      k_main/k_tail byte-identical to R14.

typedef __attribute__((ext_vector_type(8))) short short8;
typedef __attribute__((ext_vector_type(4))) float f32x4;

__device__ __forceinline__ short f2bf(float f) {
  uint32_t u = __builtin_bit_cast(uint32_t, f);
  uint32_t r = (u + 0x7fffu + ((u >> 16) & 1u)) >> 16;  // RNE
  return (short)r;
}

// ---- workspace layout (bytes) ----
#define WS_WT 16777216u    // W^T bf16          2097152
#define WS_CP 18874368u    // colsum partials   32*1024*4 = 131072
#define WS_XP 20979712u    // xpart f32         16384
#define WS_RR 20996096u    // refrow f32        16384

// ---- prep: refs colsum partials (256 blocks: 32 row-chunks x 8 col-slices),
//      W transpose (256 blocks), zero accumulators (4 blocks) ----
__global__ __launch_bounds__(256) void k_prep(
    const float* __restrict__ refs, const float* __restrict__ W,
    short* __restrict__ wt, float* __restrict__ cspart, float* __restrict__ zacc) {
  __shared__ short tile[64][68];
  const int b = blockIdx.x, t = threadIdx.x;
  if (b < 256) {
    // partial p = b>>3 covers rows [p*128, p*128+128); col-slice g = b&7 covers
    // cols [g*128, g*128+128). Thread: one col, half the rows; LDS-combine.
    __shared__ float sh[2][128];
    const int p = b >> 3, g = b & 7;
    const int c = g * 128 + (t & 127);
    const int half = t >> 7;
    const int r0 = p * 128 + half * 64;
    float s = 0.f;
    for (int r = r0; r < r0 + 64; ++r) s += refs[(size_t)r * 1024 + c];
    sh[half][t & 127] = s;
    __syncthreads();
    if (t < 128) cspart[p * 1024 + g * 128 + t] = sh[0][t] + sh[1][t];
  } else if (b < 512) {
    const int tb = b - 256;
    const int tk = (tb >> 4) * 64, tn = (tb & 15) * 64;
    const int kk = t >> 4, nn4 = (t & 15) * 4;
#pragma unroll
    for (int pp = 0; pp < 4; ++pp) {
      int k = kk + pp * 16;
      float4 v = *(const float4*)&W[(size_t)(tk + k) * 1024 + tn + nn4];
      tile[nn4 + 0][k] = f2bf(v.x);
      tile[nn4 + 1][k] = f2bf(v.y);
      tile[nn4 + 2][k] = f2bf(v.z);
      tile[nn4 + 3][k] = f2bf(v.w);
    }
    __syncthreads();
    const int nn = t >> 4, kk4 = (t & 15) * 4;
#pragma unroll
    for (int pp = 0; pp < 4; ++pp) {
      int n = nn + pp * 16;
      uint32_t lo = (uint16_t)tile[n][kk4 + 0] | ((uint32_t)(uint16_t)tile[n][kk4 + 1] << 16);
      uint32_t hi = (uint16_t)tile[n][kk4 + 2] | ((uint32_t)(uint16_t)tile[n][kk4 + 3] << 16);
      *(uint2*)&wt[(size_t)(tn + n) * 1024 + tk + kk4] = make_uint2(lo, hi);
    }
  } else {
    const int i = (b - 512) * 256 + t;
    ((float4*)zacc)[i]        = make_float4(0.f, 0.f, 0.f, 0.f);  // xpart
    ((float4*)zacc)[i + 1024] = make_float4(0.f, 0.f, 0.f, 0.f);  // refrow
  }
}

// ---- main fused GEMM: per-row sum(v^2), sum(v*t); t via gated broadcast-MFMA ----
// A from f32 x/refs (reg-staged, cvt_pk, swizzled ds_write); B via global_load_lds.
// cs_lds filled from 32 cspart partials (reduced here; no k_colsum kernel).
// 128x128 tile, BK=64, 512 thr / 8 waves (2x4), depth-2, counted vmcnt(6).
__global__ __launch_bounds__(512, 4) void k_main(
    const float* __restrict__ X, const float* __restrict__ R,
    const short* __restrict__ Wt, const float* __restrict__ bias,
    const float* __restrict__ cspart, float* __restrict__ xpart,
    float* __restrict__ refrow) {
  __shared__ __align__(16) short As[2][128 * 64];
  __shared__ __align__(16) short Bs[2][128 * 64];
  __shared__ __align__(16) short cs_lds[1024];   // bf16 colsum; reused as f32 tpan[128]
  const int t = threadIdx.x;
  const int w = t >> 6, l = t & 63;
  const int wr = w >> 2, wc = w & 3;       // 2x4 wave grid; wave tile 64 rows x 32 cols
  const int bx = blockIdx.x;
  const int nt = bx >> 6;                  // 0..7
  const int mt = bx & 63;                  // <32 -> x rows, >=32 -> refs rows
  const bool is_x = (mt < 32);
  const float* Am = is_x ? X : R;
  const int m0 = (is_x ? mt : (mt - 32)) * 128;
  const int n0 = nt * 128;

  const int srow = t >> 3;   // 0..63   (B staging)
  const int sslot = t & 7;
  const int arow = t >> 4;   // 0..31   (A staging: 32 rows x 64 f32 per issue)
  const int acol = (t & 15) * 4;
  const int asl = (t & 15) >> 1, ah = t & 1;  // 16B slot + 8B half for swizzled write

  f32x4 acc[4][2] = {};
  f32x4 acc_t[2] = {};
  float4 areg[4];

  auto stageB = [&](int buf, int kt) {
    const int k0 = kt * 64;
#pragma unroll
    for (int issue = 0; issue < 2; ++issue) {
      const int row = srow + issue * 64;
      const int sg = sslot ^ (row & 7);  // pre-swizzled global source (rule #21)
      const short* gb = Wt + ((size_t)(n0 + row) * 1024 + k0 + sg * 8);
      char* lb = (char*)&Bs[buf][0] + issue * 8192 + w * 1024;
      __builtin_amdgcn_global_load_lds(
          (const __attribute__((address_space(1))) unsigned int*)gb,
          (__attribute__((address_space(3))) unsigned int*)lb, 16, 0, 0);
    }
  };
  auto loadA = [&](int kt) {
    const int k0 = kt * 64;
#pragma unroll
    for (int i = 0; i < 4; ++i) {
      const int r = arow + i * 32;
      areg[i] = *(const float4*)&Am[(size_t)(m0 + r) * 1024 + k0 + acol];
    }
  };
  auto writeA = [&](int buf) {
#pragma unroll
    for (int i = 0; i < 4; ++i) {
      const int r = arow + i * 32;
      uint32_t lo, hi;
      asm("v_cvt_pk_bf16_f32 %0, %1, %2" : "=v"(lo) : "v"(areg[i].x), "v"(areg[i].y));
      asm("v_cvt_pk_bf16_f32 %0, %1, %2" : "=v"(hi) : "v"(areg[i].z), "v"(areg[i].w));
      char* p = (char*)&As[buf][0] + r * 128 + (((asl ^ (r & 7)) * 16) + ah * 8);
      *(uint2*)p = make_uint2(lo, hi);
    }
  };

  // prologue. loadA(0) FIRST so writeA(0)'s implicit vmem wait drains only A(0),
  // leaving B(0),B(1) in flight (drained by the counted vmcnt at iter 0/1 tops).
  loadA(0);
  stageB(0, 0);
  stageB(1, 1);
  writeA(0);
  loadA(1);
  if (is_x && t < 128) {
    // reduce 32 cspart partials for this thread's 8 columns, cvt to bf16, store
    float s0 = 0.f, s1 = 0.f, s2 = 0.f, s3 = 0.f, s4 = 0.f, s5 = 0.f, s6 = 0.f, s7 = 0.f;
#pragma unroll
    for (int p = 0; p < 32; ++p) {
      float4 c0 = *(const float4*)&cspart[p * 1024 + t * 8];
      float4 c1 = *(const float4*)&cspart[p * 1024 + t * 8 + 4];
      s0 += c0.x; s1 += c0.y; s2 += c0.z; s3 += c0.w;
      s4 += c1.x; s5 += c1.y; s6 += c1.z; s7 += c1.w;
    }
    uint32_t p0, p1, p2, p3;
    asm("v_cvt_pk_bf16_f32 %0, %1, %2" : "=v"(p0) : "v"(s0), "v"(s1));
    asm("v_cvt_pk_bf16_f32 %0, %1, %2" : "=v"(p1) : "v"(s2), "v"(s3));
    asm("v_cvt_pk_bf16_f32 %0, %1, %2" : "=v"(p2) : "v"(s4), "v"(s5));
    asm("v_cvt_pk_bf16_f32 %0, %1, %2" : "=v"(p3) : "v"(s6), "v"(s7));
    *(uint4*)&cs_lds[t * 8] = make_uint4(p0, p1, p2, p3);
  }

  // K-loop. Steady-state per-wave vmem queue at loop top: {B(kt+1):2, A(kt+2):4,
  // B(kt+2):2} -> vmcnt(6) drains exactly B(kt). lgkmcnt(0) drains own ds_writes.
  for (int kt = 0; kt < 16; ++kt) {
    if (kt < 15) asm volatile("s_waitcnt vmcnt(6) lgkmcnt(0)" ::: "memory");
    else         asm volatile("s_waitcnt vmcnt(0) lgkmcnt(0)" ::: "memory");
    __builtin_amdgcn_s_barrier();              // tile kt fully staged & visible
    const int cur = kt & 1;
    if (kt + 1 < 16) writeA((kt + 1) & 1);     // As[cur^1] read-free since prev barrier2
    if (kt + 2 < 16) loadA(kt + 2);
#pragma unroll
    for (int kk = 0; kk < 2; ++kk) {
      short8 af[4], bfr[2];
#pragma unroll
      for (int i = 0; i < 4; ++i) {
        const int ra = wr * 64 + i * 16 + (l & 15);
        const int s = (l >> 4) + kk * 4;
        af[i] = *(const short8*)&As[cur][ra * 64 + ((s ^ (ra & 7)) * 8)];
      }
#pragma unroll
      for (int j = 0; j < 2; ++j) {
        const int rbw = wc * 32 + j * 16 + (l & 15);
        const int s = (l >> 4) + kk * 4;
        bfr[j] = *(const short8*)&Bs[cur][rbw * 64 + ((s ^ (rbw & 7)) * 8)];
      }
      __builtin_amdgcn_s_setprio(1);
#pragma unroll
      for (int i = 0; i < 4; ++i)
#pragma unroll
        for (int j = 0; j < 2; ++j)
          acc[i][j] = __builtin_amdgcn_mfma_f32_16x16x32_bf16(af[i], bfr[j], acc[i][j], 0, 0, 0);
      if (is_x && wr == 0) {   // t-GEMM: once per column-group, x-blocks only
        short8 csf = *(const short8*)&cs_lds[kt * 64 + kk * 32 + (l >> 4) * 8];
#pragma unroll
        for (int j = 0; j < 2; ++j)
          acc_t[j] = __builtin_amdgcn_mfma_f32_16x16x32_bf16(csf, bfr[j], acc_t[j], 0, 0, 0);
      }
      __builtin_amdgcn_s_setprio(0);
    }
    __builtin_amdgcn_s_barrier();              // all waves done reading buf[cur]
    if (kt + 2 < 16) stageB(cur, kt + 2);      // into just-freed Bs[cur]
  }

  // share t-panel: wr==0 waves hold acc_t (rows identical; row 0 lives in lanes l<16)
  float* tpan = (float*)cs_lds;
  if (is_x) {
    if (wr == 0 && l < 16) {
      tpan[wc * 32 + l]      = acc_t[0][0];
      tpan[wc * 32 + 16 + l] = acc_t[1][0];
    }
    __syncthreads();
  }

  // epilogue: v = acc + bias[col]; per-row sums of v^2 (all) and v*t (x only)
  float bv[2], tvv[2];
#pragma unroll
  for (int n2 = 0; n2 < 2; ++n2) {
    const int ci = wc * 32 + n2 * 16 + (l & 15);
    bv[n2] = bias[n0 + ci];
    tvv[n2] = is_x ? (tpan[ci] * (1.0f / 4096.0f) + bv[n2]) : 0.f;
  }
#pragma unroll
  for (int m4 = 0; m4 < 4; ++m4) {
#pragma unroll
    for (int j = 0; j < 4; ++j) {
      if (is_x) {
        float sq = 0.f, cr = 0.f;
#pragma unroll
        for (int n2 = 0; n2 < 2; ++n2) {
          const float v = acc[m4][n2][j] + bv[n2];
          sq += v * v;
          cr += v * tvv[n2];
        }
        float comb = sq - 2.0f * cr;
#pragma unroll
        for (int off = 1; off < 16; off <<= 1) comb += __shfl_xor(comb, off, 64);
        if ((l & 15) == 0) {
          const int rm = m0 + wr * 64 + m4 * 16 + (l >> 4) * 4 + j;
          atomicAdd(&xpart[rm], comb);
        }
      } else {
        float sq = 0.f;
#pragma unroll
        for (int n2 = 0; n2 < 2; ++n2) {
          const float v = acc[m4][n2][j] + bv[n2];
          sq += v * v;
        }
#pragma unroll
        for (int off = 1; off < 16; off <<= 1) sq += __shfl_xor(sq, off, 64);
        if ((l & 15) == 0) {
          const int rm = m0 + wr * 64 + m4 * 16 + (l >> 4) * 4 + j;
          atomicAdd(&refrow[rm], sq);
        }
      }
    }
  }
}

// ---- tail: scalar = mean(refrow); out[b] = xpart[b] + scalar ----
__global__ void k_tail(const float* __restrict__ refrow, const float* __restrict__ xpart,
                       float* __restrict__ out) {
  __shared__ float sh[16];
  const int t = threadIdx.x;  // 1024 threads = 16 waves
  float s = 0.f;
  for (int i = t; i < 4096; i += 1024) s += refrow[i];
#pragma unroll
  for (int off = 32; off; off >>= 1) s += __shfl_down(s, off, 64);
  const int w = t >> 6, l = t & 63;
  if (l == 0) sh[w] = s;
  __syncthreads();
  if (t == 0) {
    float tot = 0.f;
#pragma unroll
    for (int i = 0; i < 16; ++i) tot += sh[i];
    sh[0] = tot * (1.0f / 4096.0f);
  }
  __syncthreads();
  const float ms = sh[0];
  for (int i = t; i < 4096; i += 1024) out[i] = xpart[i] + ms;
}

extern "C" void kernel_launch(void* const* d_in, const int* in_sizes, int n_in,
                              void* d_out, int out_size, void* d_ws, size_t ws_size,
                              hipStream_t stream) {
  const float* x    = (const float*)d_in[0];
  const float* refs = (const float*)d_in[1];
  const float* W    = (const float*)d_in[2];
  const float* bias = (const float*)d_in[3];
  float* out = (float*)d_out;
  char* ws = (char*)d_ws;

  short* wt     = (short*)(ws + WS_WT);
  float* cspart = (float*)(ws + WS_CP);
  float* xpart  = (float*)(ws + WS_XP);
  float* refrow = (float*)(ws + WS_RR);

  hipLaunchKernelGGL(k_prep, dim3(516), dim3(256), 0, stream, refs, W, wt, cspart, xpart);
  hipLaunchKernelGGL(k_main, dim3(512), dim3(512), 0, stream, x, refs, wt, bias, cspart, xpart, refrow);
  hipLaunchKernelGGL(k_tail, dim3(1), dim3(1024), 0, stream, refrow, xpart, out);
}

// Round 16
// 44.527 us; speedup vs baseline: 1.3539x; 1.3539x over previous
//
#include <hip/hip_runtime.h>
#include <hip/hip_bf16.h>
#include <stdint.h>

// RefBasedDeepMetric: out[b] = ||x_b@W + b||^2 + mean_r||vref_r||^2 - 2*(x_b@W + b).t
// t = (mean_r refs_r)@W + b.  Two row-norm-reduced 4096x1024x1024 GEMMs, fused epilogues.
// R7: XCD co-location (mt=bx&63, nt=bx>>6). R9: f32 A staged direct (cvt_pk in k_main).
// R10: t-vector via broadcast-MFMA (k_tvec dropped). R11: gated t-MFMA + counted
// vmcnt(6) + early writeA. 44.6us == BEST.
// R12-R15: four structural variants (kernel split, in-kernel handoff, colsum fold,
// prep re-parallelize) ALL regressed (51.5/60.7/50.8/60.3). Lessons: cross-block deps
// live at launch boundaries; k_main's prologue vmem queue must stay exactly as traced.
// R16: revert to R11 verbatim.

typedef __attribute__((ext_vector_type(8))) short short8;
typedef __attribute__((ext_vector_type(4))) float f32x4;

__device__ __forceinline__ short f2bf(float f) {
  uint32_t u = __builtin_bit_cast(uint32_t, f);
  uint32_t r = (u + 0x7fffu + ((u >> 16) & 1u)) >> 16;  // RNE
  return (short)r;
}
__device__ __forceinline__ float bf2f(short s) {
  uint32_t u = ((uint32_t)(uint16_t)s) << 16;
  return __builtin_bit_cast(float, u);
}

// ---- workspace layout (bytes) ----
#define WS_WT 16777216u    // W^T bf16          2097152
#define WS_CP 18874368u    // colsum partials   512*1024*4 = 2097152
#define WS_CS 20971520u    // colsum f32        4096
#define WS_XP 20979712u    // xpart f32         16384
#define WS_RR 20996096u    // refrow f32        16384

// ---- prep: refs colsum partials, W transpose, zero accumulators ----
__global__ __launch_bounds__(256) void k_prep(
    const float* __restrict__ refs, const float* __restrict__ W,
    short* __restrict__ wt, float* __restrict__ cspart, float* __restrict__ zacc) {
  __shared__ short tile[64][68];
  const int b = blockIdx.x, t = threadIdx.x;
  if (b < 512) {
    const int rblk = b;
    const int c0 = t * 4;
    float s0 = 0.f, s1 = 0.f, s2 = 0.f, s3 = 0.f;
    for (int r = rblk * 8; r < rblk * 8 + 8; ++r) {
      float4 v = *(const float4*)&refs[(size_t)r * 1024 + c0];
      s0 += v.x; s1 += v.y; s2 += v.z; s3 += v.w;
    }
    cspart[rblk * 1024 + c0 + 0] = s0;
    cspart[rblk * 1024 + c0 + 1] = s1;
    cspart[rblk * 1024 + c0 + 2] = s2;
    cspart[rblk * 1024 + c0 + 3] = s3;
  } else if (b < 768) {
    const int tb = b - 512;
    const int tk = (tb >> 4) * 64, tn = (tb & 15) * 64;
    const int kk = t >> 4, nn4 = (t & 15) * 4;
#pragma unroll
    for (int p = 0; p < 4; ++p) {
      int k = kk + p * 16;
      float4 v = *(const float4*)&W[(size_t)(tk + k) * 1024 + tn + nn4];
      tile[nn4 + 0][k] = f2bf(v.x);
      tile[nn4 + 1][k] = f2bf(v.y);
      tile[nn4 + 2][k] = f2bf(v.z);
      tile[nn4 + 3][k] = f2bf(v.w);
    }
    __syncthreads();
    const int nn = t >> 4, kk4 = (t & 15) * 4;
#pragma unroll
    for (int p = 0; p < 4; ++p) {
      int n = nn + p * 16;
      uint32_t lo = (uint16_t)tile[n][kk4 + 0] | ((uint32_t)(uint16_t)tile[n][kk4 + 1] << 16);
      uint32_t hi = (uint16_t)tile[n][kk4 + 2] | ((uint32_t)(uint16_t)tile[n][kk4 + 3] << 16);
      *(uint2*)&wt[(size_t)(tn + n) * 1024 + tk + kk4] = make_uint2(lo, hi);
    }
  } else {
    const int i = (b - 768) * 256 + t;
    ((float4*)zacc)[i]        = make_float4(0.f, 0.f, 0.f, 0.f);
    ((float4*)zacc)[i + 1024] = make_float4(0.f, 0.f, 0.f, 0.f);
  }
}

// ---- colsum[k] = sum_p cspart[p][k] ----
__global__ void k_colsum(const float* __restrict__ cspart, float* __restrict__ colsum) {
  __shared__ float sh[8][32];
  const int t = threadIdx.x;
  const int c = t & 31, pg = t >> 5;
  const int k = blockIdx.x * 32 + c;
  float s = 0.f;
  for (int i = 0; i < 64; ++i) s += cspart[(size_t)(pg * 64 + i) * 1024 + k];
  sh[pg][c] = s;
  __syncthreads();
  if (t < 32) {
    float tot = 0.f;
#pragma unroll
    for (int g = 0; g < 8; ++g) tot += sh[g][t];
    colsum[blockIdx.x * 32 + t] = tot;
  }
}

// ---- main fused GEMM: per-row sum(v^2), sum(v*t); t via gated broadcast-MFMA ----
// A from f32 x/refs (reg-staged, cvt_pk, swizzled ds_write); B via global_load_lds.
// 128x128 tile, BK=64, 512 thr / 8 waves (2x4), depth-2, counted vmcnt(6).
__global__ __launch_bounds__(512, 4) void k_main(
    const float* __restrict__ X, const float* __restrict__ R,
    const short* __restrict__ Wt, const float* __restrict__ bias,
    const float* __restrict__ colsum, float* __restrict__ xpart,
    float* __restrict__ refrow) {
  __shared__ __align__(16) short As[2][128 * 64];
  __shared__ __align__(16) short Bs[2][128 * 64];
  __shared__ __align__(16) short cs_lds[1024];   // bf16 colsum; reused as f32 tpan[128] post-loop
  const int t = threadIdx.x;
  const int w = t >> 6, l = t & 63;
  const int wr = w >> 2, wc = w & 3;       // 2x4 wave grid; wave tile 64 rows x 32 cols
  const int bx = blockIdx.x;
  const int nt = bx >> 6;                  // 0..7
  const int mt = bx & 63;                  // <32 -> x rows, >=32 -> refs rows
  const bool is_x = (mt < 32);
  const float* Am = is_x ? X : R;
  const int m0 = (is_x ? mt : (mt - 32)) * 128;
  const int n0 = nt * 128;

  const int srow = t >> 3;   // 0..63   (B staging)
  const int sslot = t & 7;
  const int arow = t >> 4;   // 0..31   (A staging: 32 rows x 64 f32 per issue)
  const int acol = (t & 15) * 4;
  const int asl = (t & 15) >> 1, ah = t & 1;  // 16B slot + 8B half for swizzled write

  f32x4 acc[4][2] = {};
  f32x4 acc_t[2] = {};
  float4 areg[4];

  auto stageB = [&](int buf, int kt) {
    const int k0 = kt * 64;
#pragma unroll
    for (int issue = 0; issue < 2; ++issue) {
      const int row = srow + issue * 64;
      const int sg = sslot ^ (row & 7);  // pre-swizzled global source (rule #21)
      const short* gb = Wt + ((size_t)(n0 + row) * 1024 + k0 + sg * 8);
      char* lb = (char*)&Bs[buf][0] + issue * 8192 + w * 1024;
      __builtin_amdgcn_global_load_lds(
          (const __attribute__((address_space(1))) unsigned int*)gb,
          (__attribute__((address_space(3))) unsigned int*)lb, 16, 0, 0);
    }
  };
  auto loadA = [&](int kt) {
    const int k0 = kt * 64;
#pragma unroll
    for (int i = 0; i < 4; ++i) {
      const int r = arow + i * 32;
      areg[i] = *(const float4*)&Am[(size_t)(m0 + r) * 1024 + k0 + acol];
    }
  };
  auto writeA = [&](int buf) {
#pragma unroll
    for (int i = 0; i < 4; ++i) {
      const int r = arow + i * 32;
      uint32_t lo, hi;
      asm("v_cvt_pk_bf16_f32 %0, %1, %2" : "=v"(lo) : "v"(areg[i].x), "v"(areg[i].y));
      asm("v_cvt_pk_bf16_f32 %0, %1, %2" : "=v"(hi) : "v"(areg[i].z), "v"(areg[i].w));
      char* p = (char*)&As[buf][0] + r * 128 + (((asl ^ (r & 7)) * 16) + ah * 8);
      *(uint2*)p = make_uint2(lo, hi);
    }
  };

  // prologue. loadA(0) FIRST so writeA(0)'s implicit vmem wait drains only A(0),
  // leaving B(0),B(1) in flight (drained by the counted vmcnt at iter 0/1 tops).
  loadA(0);
  stageB(0, 0);
  stageB(1, 1);
  writeA(0);
  loadA(1);
  if (is_x && t < 128) {
    float4 c0 = *(const float4*)&colsum[t * 8];
    float4 c1 = *(const float4*)&colsum[t * 8 + 4];
    uint32_t p0, p1, p2, p3;
    asm("v_cvt_pk_bf16_f32 %0, %1, %2" : "=v"(p0) : "v"(c0.x), "v"(c0.y));
    asm("v_cvt_pk_bf16_f32 %0, %1, %2" : "=v"(p1) : "v"(c0.z), "v"(c0.w));
    asm("v_cvt_pk_bf16_f32 %0, %1, %2" : "=v"(p2) : "v"(c1.x), "v"(c1.y));
    asm("v_cvt_pk_bf16_f32 %0, %1, %2" : "=v"(p3) : "v"(c1.z), "v"(c1.w));
    *(uint4*)&cs_lds[t * 8] = make_uint4(p0, p1, p2, p3);
  }

  // K-loop. Steady-state per-wave vmem queue at loop top: {B(kt+1):2, A(kt+2):4,
  // B(kt+2):2} -> vmcnt(6) drains exactly B(kt). lgkmcnt(0) drains own ds_writes.
  for (int kt = 0; kt < 16; ++kt) {
    if (kt < 15) asm volatile("s_waitcnt vmcnt(6) lgkmcnt(0)" ::: "memory");
    else         asm volatile("s_waitcnt vmcnt(0) lgkmcnt(0)" ::: "memory");
    __builtin_amdgcn_s_barrier();              // tile kt fully staged & visible
    const int cur = kt & 1;
    // issue next A-tile conversion+writes now: As[cur^1] is read-free since the
    // previous barrier2; stalls (cvt's A-load wait, ds_writes) hide under MFMA.
    if (kt + 1 < 16) writeA((kt + 1) & 1);
    if (kt + 2 < 16) loadA(kt + 2);            // areg free after writeA consumed it
#pragma unroll
    for (int kk = 0; kk < 2; ++kk) {
      short8 af[4], bfr[2];
#pragma unroll
      for (int i = 0; i < 4; ++i) {
        const int ra = wr * 64 + i * 16 + (l & 15);
        const int s = (l >> 4) + kk * 4;
        af[i] = *(const short8*)&As[cur][ra * 64 + ((s ^ (ra & 7)) * 8)];
      }
#pragma unroll
      for (int j = 0; j < 2; ++j) {
        const int rbw = wc * 32 + j * 16 + (l & 15);
        const int s = (l >> 4) + kk * 4;
        bfr[j] = *(const short8*)&Bs[cur][rbw * 64 + ((s ^ (rbw & 7)) * 8)];
      }
      __builtin_amdgcn_s_setprio(1);
#pragma unroll
      for (int i = 0; i < 4; ++i)
#pragma unroll
        for (int j = 0; j < 2; ++j)
          acc[i][j] = __builtin_amdgcn_mfma_f32_16x16x32_bf16(af[i], bfr[j], acc[i][j], 0, 0, 0);
      if (is_x && wr == 0) {   // t-GEMM needed once per column-group, x-blocks only
        short8 csf = *(const short8*)&cs_lds[kt * 64 + kk * 32 + (l >> 4) * 8];
#pragma unroll
        for (int j = 0; j < 2; ++j)
          acc_t[j] = __builtin_amdgcn_mfma_f32_16x16x32_bf16(csf, bfr[j], acc_t[j], 0, 0, 0);
      }
      __builtin_amdgcn_s_setprio(0);
    }
    __builtin_amdgcn_s_barrier();              // all waves done reading buf[cur]
    if (kt + 2 < 16) stageB(cur, kt + 2);      // into just-freed Bs[cur]
  }

  // share t-panel: wr==0 waves hold acc_t (rows identical; take row 0 from lanes l<16)
  float* tpan = (float*)cs_lds;
  if (is_x) {
    if (wr == 0 && l < 16) {
      tpan[wc * 32 + l]      = acc_t[0][0];
      tpan[wc * 32 + 16 + l] = acc_t[1][0];
    }
    __syncthreads();
  }

  // epilogue: v = acc + bias[col]; per-row sums of v^2 (all) and v*t (x only)
  float bv[2], tvv[2];
#pragma unroll
  for (int n2 = 0; n2 < 2; ++n2) {
    const int ci = wc * 32 + n2 * 16 + (l & 15);
    bv[n2] = bias[n0 + ci];
    tvv[n2] = is_x ? (tpan[ci] * (1.0f / 4096.0f) + bv[n2]) : 0.f;
  }
#pragma unroll
  for (int m4 = 0; m4 < 4; ++m4) {
#pragma unroll
    for (int j = 0; j < 4; ++j) {
      if (is_x) {
        float sq = 0.f, cr = 0.f;
#pragma unroll
        for (int n2 = 0; n2 < 2; ++n2) {
          const float v = acc[m4][n2][j] + bv[n2];
          sq += v * v;
          cr += v * tvv[n2];
        }
        float comb = sq - 2.0f * cr;
#pragma unroll
        for (int off = 1; off < 16; off <<= 1) comb += __shfl_xor(comb, off, 64);
        if ((l & 15) == 0) {
          const int rm = m0 + wr * 64 + m4 * 16 + (l >> 4) * 4 + j;
          atomicAdd(&xpart[rm], comb);
        }
      } else {
        float sq = 0.f;
#pragma unroll
        for (int n2 = 0; n2 < 2; ++n2) {
          const float v = acc[m4][n2][j] + bv[n2];
          sq += v * v;
        }
#pragma unroll
        for (int off = 1; off < 16; off <<= 1) sq += __shfl_xor(sq, off, 64);
        if ((l & 15) == 0) {
          const int rm = m0 + wr * 64 + m4 * 16 + (l >> 4) * 4 + j;
          atomicAdd(&refrow[rm], sq);
        }
      }
    }
  }
}

// ---- tail: scalar = mean(refrow); out[b] = xpart[b] + scalar ----
__global__ void k_tail(const float* __restrict__ refrow, const float* __restrict__ xpart,
                       float* __restrict__ out) {
  __shared__ float sh[16];
  const int t = threadIdx.x;  // 1024 threads = 16 waves
  float s = 0.f;
  for (int i = t; i < 4096; i += 1024) s += refrow[i];
#pragma unroll
  for (int off = 32; off; off >>= 1) s += __shfl_down(s, off, 64);
  const int w = t >> 6, l = t & 63;
  if (l == 0) sh[w] = s;
  __syncthreads();
  if (t == 0) {
    float tot = 0.f;
#pragma unroll
    for (int i = 0; i < 16; ++i) tot += sh[i];
    sh[0] = tot * (1.0f / 4096.0f);
  }
  __syncthreads();
  const float ms = sh[0];
  for (int i = t; i < 4096; i += 1024) out[i] = xpart[i] + ms;
}

extern "C" void kernel_launch(void* const* d_in, const int* in_sizes, int n_in,
                              void* d_out, int out_size, void* d_ws, size_t ws_size,
                              hipStream_t stream) {
  const float* x    = (const float*)d_in[0];
  const float* refs = (const float*)d_in[1];
  const float* W    = (const float*)d_in[2];
  const float* bias = (const float*)d_in[3];
  float* out = (float*)d_out;
  char* ws = (char*)d_ws;

  short* wt     = (short*)(ws + WS_WT);
  float* cspart = (float*)(ws + WS_CP);
  float* colsum = (float*)(ws + WS_CS);
  float* xpart  = (float*)(ws + WS_XP);
  float* refrow = (float*)(ws + WS_RR);

  hipLaunchKernelGGL(k_prep, dim3(772), dim3(256), 0, stream, refs, W, wt, cspart, xpart);
  hipLaunchKernelGGL(k_colsum, dim3(32), dim3(256), 0, stream, cspart, colsum);
  hipLaunchKernelGGL(k_main, dim3(512), dim3(512), 0, stream, x, refs, wt, bias, colsum, xpart, refrow);
  hipLaunchKernelGGL(k_tail, dim3(1), dim3(1024), 0, stream, refrow, xpart, out);
}